// Round 12
// baseline (142.975 us; speedup 1.0000x reference)
//
#include <hip/hip_runtime.h>
#include <math.h>

#define R 1000
#define NC 81
#define CAP 1024       // >= R, compaction can never overflow
#define NT 512
#define NBLK 256       // total blocks: 2048 waves -> one row per wave
#define NCONS 80       // consumer blocks (one per foreground class)
#define SUPMAX 512     // matrix-NMS path handles V <= SUPMAX
#define WMAX 8         // SUPMAX / 64 keep-words
#define PT_LD 1024     // probT leading dim
#define MAGIC 0x5EEDF00Du   // != 0xAAAAAAAA poison

// ONE kernel node. Phase 1 (all 256 blocks): wave-per-row softmax -> probT
// (2048 waves, <=1 row each -> dependent shfl chain fully hidden; this is
// R8's proven-fast kernel-A arithmetic). Producer->consumer handoff via
// per-block release flags (no 35us grid.sync, no second node, no memset:
// MAGIC != poison). Blocks 80..255 exit; blocks 0..79 acquire-spin then run
// R8's kernel-B body. Liveness: 256 blocks @ ~69KB LDS are all co-resident;
// producers never wait. G16: agent-scope acquire/release + threadfence.
__global__ __launch_bounds__(NT) void frcnn_onenode_kernel(
    const float* __restrict__ roi,        // [R,4]
    const float* __restrict__ roi_loc,    // [R, NC*4]
    const float* __restrict__ roi_score,  // [R, NC]
    unsigned*    __restrict__ flags,      // [NBLK] in d_ws
    float*       __restrict__ probT,      // [NC*PT_LD] in d_ws
    float* __restrict__ out)              // [80*R*5] boxes+score, then [80*R] labels
{
    const int tid  = threadIdx.x;
    const int bid  = blockIdx.x;
    const int wid  = tid >> 6;
    const int lane = tid & 63;

    // ---- phase 1: one row per wave ----
    const int r = bid * (NT / 64) + wid;      // global wave id == row id
    if (r < R) {
        const float* sc = roi_score + r * NC;
        float v0 = sc[lane];
        float v1 = (lane < NC - 64) ? sc[lane + 64] : -INFINITY;
        float m = fmaxf(v0, v1);
        #pragma unroll
        for (int off = 32; off > 0; off >>= 1)
            m = fmaxf(m, __shfl_xor(m, off, 64));
        float e0 = expf(v0 - m);
        float e1 = (lane < NC - 64) ? expf(v1 - m) : 0.0f;
        float e = e0 + e1;
        #pragma unroll
        for (int off = 32; off > 0; off >>= 1)
            e += __shfl_xor(e, off, 64);
        float rcp = 1.0f / e;
        probT[lane * PT_LD + r] = e0 * rcp;              // class = lane
        if (lane < NC - 64)
            probT[(lane + 64) * PT_LD + r] = e1 * rcp;   // class = lane+64
    }
    __syncthreads();
    __threadfence();                                     // device-scope release
    if (tid == 0)
        __hip_atomic_store(&flags[bid], MAGIC, __ATOMIC_RELEASE,
                           __HIP_MEMORY_SCOPE_AGENT);

    if (bid >= NCONS) return;                            // producers done

    // ---- consumer: wait for all 256 producer flags ----
    for (int f = tid; f < NBLK; f += NT) {
        while (__hip_atomic_load(&flags[f], __ATOMIC_ACQUIRE,
                                 __HIP_MEMORY_SCOPE_AGENT) != MAGIC)
            __builtin_amdgcn_s_sleep(2);
    }
    __syncthreads();

    const int c = bid + 1;                               // class 1..80

    __shared__ float s_score[CAP];
    __shared__ int   s_idx[CAP];
    __shared__ float s_ss[CAP];
    __shared__ float s_y0[CAP], s_x0[CAP], s_y1[CAP], s_x1[CAP], s_area[CAP];
    __shared__ int   s_keepi[CAP];
    __shared__ unsigned long long s_sup[SUPMAX * WMAX];
    __shared__ unsigned long long s_kw[WMAX];
    __shared__ int   s_cnt;

    if (tid == 0) s_cnt = 0;
    __syncthreads();

    // 1. compact valid (p > 0.05): coalesced contiguous read
    const float* pc = probT + c * PT_LD;
    for (int rr = tid; rr < R; rr += NT) {
        float p = pc[rr];
        if (p > 0.05f) {
            int slot = atomicAdd(&s_cnt, 1);
            s_score[slot] = p;
            s_idx[slot]   = rr;
        }
    }
    __syncthreads();
    const int V = s_cnt;

    // 2. rank-sort (stable argsort by (-score, idx)) + fused decode
    for (int p = tid; p < V; p += NT) {
        float sp = s_score[p];
        int   ip = s_idx[p];
        int rank = 0;
        for (int q = 0; q < V; ++q) {
            float sq = s_score[q];
            int   iq = s_idx[q];
            rank += (sq > sp) || (sq == sp && iq < ip);
        }
        float ry0 = roi[ip*4+0], rx0 = roi[ip*4+1];
        float ry1 = roi[ip*4+2], rx1 = roi[ip*4+3];
        float h = ry1 - ry0, w = rx1 - rx0;
        float cy = ry0 + 0.5f*h, cx = rx0 + 0.5f*w;
        const float* lp = roi_loc + (size_t)ip*(NC*4) + c*4;
        float dy = lp[0]*0.1f, dx = lp[1]*0.1f;
        float dh = lp[2]*0.2f, dw = lp[3]*0.2f;
        float ny = dy*h + cy, nx = dx*w + cx;
        float nh = expf(dh)*h, nw = expf(dw)*w;
        float y0 = ny - 0.5f*nh, x0 = nx - 0.5f*nw;
        float y1 = ny + 0.5f*nh, x1 = nx + 0.5f*nw;
        y0 = fminf(fmaxf(y0, 0.f), 600.f);
        x0 = fminf(fmaxf(x0, 0.f), 800.f);
        y1 = fminf(fmaxf(y1, 0.f), 600.f);
        x1 = fminf(fmaxf(x1, 0.f), 800.f);
        s_ss[rank] = sp;
        s_y0[rank] = y0; s_x0[rank] = x0; s_y1[rank] = y1; s_x1[rank] = x1;
        s_area[rank] = (y1 - y0) * (x1 - x0);
        s_keepi[rank] = 1;
    }
    __syncthreads();

    // 3. NMS
    if (V > 0 && V <= SUPMAX) {
        const int W = (V + 63) >> 6;
        // 3a. suppression bit-matrix, one row per thread
        for (int i = tid; i < V; i += NT) {
            float ay0 = s_y0[i], ax0 = s_x0[i];
            float ay1 = s_y1[i], ax1 = s_x1[i];
            float aa  = s_area[i];
            for (int w = 0; w < W; ++w) {
                int j0 = w * 64;
                int js = (i + 1 > j0) ? i + 1 : j0;
                int je = (j0 + 64 < V) ? j0 + 64 : V;
                unsigned long long bits = 0ull;
                for (int j = js; j < je; ++j) {
                    float ty = fmaxf(ay0, s_y0[j]);
                    float tx = fmaxf(ax0, s_x0[j]);
                    float by = fminf(ay1, s_y1[j]);
                    float bx = fminf(ax1, s_x1[j]);
                    float hh = fmaxf(by - ty, 0.f);
                    float ww = fmaxf(bx - tx, 0.f);
                    float inter = hh * ww;
                    float iou = inter / (aa + s_area[j] - inter + 1e-9f);
                    if (iou > 0.5f) bits |= (1ull << (j - j0));
                }
                s_sup[i * W + w] = bits;
            }
        }
        __syncthreads();
        // 3b. serial scan in thread-0 registers, next row prefetched
        if (tid == 0) {
            unsigned long long kw[WMAX];
            #pragma unroll
            for (int w = 0; w < WMAX; ++w) {
                int full = V - w * 64;
                kw[w] = (full >= 64) ? ~0ull : (full > 0 ? ((1ull << full) - 1ull) : 0ull);
            }
            unsigned long long rowb[WMAX], nxtb[WMAX];
            #pragma unroll
            for (int w = 0; w < WMAX; ++w) rowb[w] = (w < W) ? s_sup[w] : 0ull;
            #pragma unroll
            for (int w = 0; w < WMAX; ++w) {
                if (w * 64 < V) {
                    unsigned long long cur = kw[w];
                    int lim = V - w * 64; if (lim > 64) lim = 64;
                    for (int b = 0; b < lim; ++b) {
                        int nxt = w * 64 + b + 1;           // prefetch next row
                        if (nxt < V) {
                            #pragma unroll
                            for (int w2 = 0; w2 < WMAX; ++w2)
                                if (w2 < W) nxtb[w2] = s_sup[nxt * W + w2];
                        }
                        if ((cur >> b) & 1ull) {
                            cur &= ~rowb[w];
                            #pragma unroll
                            for (int w2 = 0; w2 < WMAX; ++w2)
                                if (w2 > w && w2 < W) kw[w2] &= ~rowb[w2];
                        }
                        #pragma unroll
                        for (int w2 = 0; w2 < WMAX; ++w2) rowb[w2] = nxtb[w2];
                    }
                    kw[w] = cur;
                }
            }
            #pragma unroll
            for (int w = 0; w < WMAX; ++w) s_kw[w] = kw[w];
        }
        __syncthreads();
    } else if (V > SUPMAX) {
        // fallback: sequential-i / parallel-j greedy (correct for any V)
        for (int i = 0; i < V; ++i) {
            if (s_keepi[i]) {
                float ay0 = s_y0[i], ax0 = s_x0[i];
                float ay1 = s_y1[i], ax1 = s_x1[i];
                float aa  = s_area[i];
                for (int jj = i + 1 + tid; jj < V; jj += NT) {
                    float ty = fmaxf(ay0, s_y0[jj]);
                    float tx = fmaxf(ax0, s_x0[jj]);
                    float by = fminf(ay1, s_y1[jj]);
                    float bx = fminf(ax1, s_x1[jj]);
                    float hh = fmaxf(by - ty, 0.f);
                    float ww = fmaxf(bx - tx, 0.f);
                    float inter = hh * ww;
                    float iou = inter / (aa + s_area[jj] - inter + 1e-9f);
                    if (iou > 0.5f) s_keepi[jj] = 0;
                }
            }
            __syncthreads();
        }
    }

    // 4. write outputs (covers full buffer; no memset needed)
    const bool matrix_path = (V <= SUPMAX);
    float* out0 = out + (size_t)(c - 1) * R * 5;
    float* out1 = out + (size_t)80 * R * 5 + (size_t)(c - 1) * R;
    for (int p = tid; p < R; p += NT) {
        bool kept = false;
        if (p < V)
            kept = matrix_path ? (((s_kw[p >> 6] >> (p & 63)) & 1ull) != 0ull)
                               : (s_keepi[p] != 0);
        float y0 = 0.f, x0 = 0.f, y1 = 0.f, x1 = 0.f, s = 0.f, lab = -1.0f;
        if (kept) {
            y0 = s_y0[p]; x0 = s_x0[p]; y1 = s_y1[p]; x1 = s_x1[p];
            s  = s_ss[p];
            lab = (float)(c - 1);
        }
        out0[p*5+0] = y0; out0[p*5+1] = x0; out0[p*5+2] = y1;
        out0[p*5+3] = x1; out0[p*5+4] = s;
        out1[p] = lab;
    }
}

extern "C" void kernel_launch(void* const* d_in, const int* in_sizes, int n_in,
                              void* d_out, int out_size, void* d_ws, size_t ws_size,
                              hipStream_t stream) {
    const float* roi       = (const float*)d_in[0];
    const float* roi_loc   = (const float*)d_in[1];
    const float* roi_score = (const float*)d_in[2];
    float* out = (float*)d_out;

    unsigned* flags = (unsigned*)d_ws;                  // [256]
    float*    probT = (float*)((char*)d_ws + 1024);     // [NC * PT_LD]

    hipLaunchKernelGGL(frcnn_onenode_kernel, dim3(NBLK), dim3(NT), 0, stream,
                       roi, roi_loc, roi_score, flags, probT, out);
}

// Round 13
// 96.031 us; speedup vs baseline: 1.4888x; 1.4888x over previous
//
#include <hip/hip_runtime.h>
#include <math.h>

#define R 1000
#define NC 81
#define CAP 1024       // >= R, compaction can never overflow
#define NTA 256        // kernel A block size
#define NTB 256        // kernel B block size (4 waves)
#define NPASS ((R + NTB - 1) / NTB)   // 4 compact passes
#define SUPMAX 512     // matrix-NMS path handles V <= SUPMAX
#define WMAX 8         // SUPMAX / 64 keep-words
#define PT_LD 1024     // probT leading dim

// ---- Kernel A (unchanged from R8, proven): wave-per-RoI softmax -> probT --
__global__ __launch_bounds__(NTA) void softmax_probT_kernel(
    const float* __restrict__ roi_score,  // [R, NC]
    float* __restrict__ probT)            // [NC * PT_LD]
{
    const int wid  = threadIdx.x >> 6;
    const int lane = threadIdx.x & 63;
    const int r    = blockIdx.x * 4 + wid;
    if (r >= R) return;
    const float* sc = roi_score + r * NC;
    float v0 = sc[lane];
    float v1 = (lane < NC - 64) ? sc[lane + 64] : -INFINITY;
    float m = fmaxf(v0, v1);
    #pragma unroll
    for (int off = 32; off > 0; off >>= 1)
        m = fmaxf(m, __shfl_xor(m, off, 64));
    float e0 = expf(v0 - m);
    float e1 = (lane < NC - 64) ? expf(v1 - m) : 0.0f;
    float e = e0 + e1;
    #pragma unroll
    for (int off = 32; off > 0; off >>= 1)
        e += __shfl_xor(e, off, 64);
    float rcp = 1.0f / e;
    probT[lane * PT_LD + r] = e0 * rcp;
    if (lane < NC - 64)
        probT[(lane + 64) * PT_LD + r] = e1 * rcp;
}

// ---- Kernel B: compact+decode(regs) -> rank -> scatter -> NMS -> write ----
__global__ __launch_bounds__(NTB) void frcnn_classB_kernel(
    const float* __restrict__ roi,        // [R,4]
    const float* __restrict__ roi_loc,    // [R, NC*4]
    const float* __restrict__ probT,      // [NC * PT_LD]
    float* __restrict__ out)              // [80*R*5] boxes+score, then [80*R] labels
{
    const int c   = blockIdx.x + 1;       // class 1..80
    const int tid = threadIdx.x;

    __shared__ float s_sc[CAP];           // compact-order scores
    __shared__ int   s_id[CAP];           // compact-order roi idx
    __shared__ int   s_rank[CAP];         // rank; aliased as keep[] in fallback
    __shared__ float s_ss[CAP];           // sorted score
    __shared__ float s_y0[CAP], s_x0[CAP], s_y1[CAP], s_x1[CAP], s_area[CAP];
    __shared__ unsigned long long s_sup[SUPMAX * WMAX];
    __shared__ unsigned long long s_kw[WMAX];
    __shared__ int   s_cnt;

    if (tid == 0) s_cnt = 0;
    __syncthreads();

    // ---- 1. compact + FUSED decode into registers (static per-pass slots) --
    // Scattered roi/roi_loc loads issue here, in parallel across finder
    // threads, overlapped with the compact scan itself (R8 did them after
    // the sort barrier, as a dependent chain).
    bool  fnd[NPASS];
    int   slt[NPASS];
    float qy0[NPASS], qx0[NPASS], qy1[NPASS], qx1[NPASS], qar[NPASS], qsc[NPASS];
    const float* pc = probT + c * PT_LD;
    #pragma unroll
    for (int ps = 0; ps < NPASS; ++ps) {
        fnd[ps] = false;
        int r = tid + ps * NTB;
        if (r < R) {
            float p = pc[r];
            if (p > 0.05f) {
                int slot = atomicAdd(&s_cnt, 1);   // LDS atomic
                s_sc[slot] = p;
                s_id[slot] = r;
                float ry0 = roi[r*4+0], rx0 = roi[r*4+1];
                float ry1 = roi[r*4+2], rx1 = roi[r*4+3];
                float h = ry1 - ry0, w = rx1 - rx0;
                float cy = ry0 + 0.5f*h, cx = rx0 + 0.5f*w;
                const float* lp = roi_loc + (size_t)r*(NC*4) + c*4;
                float dy = lp[0]*0.1f, dx = lp[1]*0.1f;
                float dh = lp[2]*0.2f, dw = lp[3]*0.2f;
                float ny = dy*h + cy, nx = dx*w + cx;
                float nh = expf(dh)*h, nw = expf(dw)*w;
                float y0 = ny - 0.5f*nh, x0 = nx - 0.5f*nw;
                float y1 = ny + 0.5f*nh, x1 = nx + 0.5f*nw;
                y0 = fminf(fmaxf(y0, 0.f), 600.f);
                x0 = fminf(fmaxf(x0, 0.f), 800.f);
                y1 = fminf(fmaxf(y1, 0.f), 600.f);
                x1 = fminf(fmaxf(x1, 0.f), 800.f);
                fnd[ps] = true; slt[ps] = slot; qsc[ps] = p;
                qy0[ps] = y0; qx0[ps] = x0; qy1[ps] = y1; qx1[ps] = x1;
                qar[ps] = (y1 - y0) * (x1 - x0);
            }
        }
    }
    __syncthreads();
    const int V = s_cnt;

    // ---- 2. rank = stable-argsort position by (-score, idx) ----
    for (int p = tid; p < V; p += NTB) {
        float sp = s_sc[p];
        int   ip = s_id[p];
        int rank = 0;
        for (int q = 0; q < V; ++q) {
            float sq = s_sc[q];
            int   iq = s_id[q];
            rank += (sq > sp) || (sq == sp && iq < ip);
        }
        s_rank[p] = rank;
    }
    __syncthreads();

    // ---- 3. scatter register-held boxes to sorted slots ----
    #pragma unroll
    for (int ps = 0; ps < NPASS; ++ps) {
        if (fnd[ps]) {
            int rk = s_rank[slt[ps]];
            s_ss[rk]   = qsc[ps];
            s_y0[rk]   = qy0[ps]; s_x0[rk] = qx0[ps];
            s_y1[rk]   = qy1[ps]; s_x1[rk] = qx1[ps];
            s_area[rk] = qar[ps];
        }
    }
    __syncthreads();

    // ---- 4. NMS ----
    int* s_keepi = s_rank;                // rank[] dead from here; alias as keep
    if (V > 0 && V <= SUPMAX) {
        const int W = (V + 63) >> 6;
        // 4a. suppression bit-matrix, rows strided over all threads
        for (int i = tid; i < V; i += NTB) {
            float ay0 = s_y0[i], ax0 = s_x0[i];
            float ay1 = s_y1[i], ax1 = s_x1[i];
            float aa  = s_area[i];
            for (int w = 0; w < W; ++w) {
                int j0 = w * 64;
                int js = (i + 1 > j0) ? i + 1 : j0;
                int je = (j0 + 64 < V) ? j0 + 64 : V;
                unsigned long long bits = 0ull;
                for (int j = js; j < je; ++j) {
                    float ty = fmaxf(ay0, s_y0[j]);
                    float tx = fmaxf(ax0, s_x0[j]);
                    float by = fminf(ay1, s_y1[j]);
                    float bx = fminf(ax1, s_x1[j]);
                    float hh = fmaxf(by - ty, 0.f);
                    float ww = fmaxf(bx - tx, 0.f);
                    float inter = hh * ww;
                    float iou = inter / (aa + s_area[j] - inter + 1e-9f);
                    if (iou > 0.5f) bits |= (1ull << (j - j0));
                }
                s_sup[i * W + w] = bits;
            }
        }
        __syncthreads();
        // 4b. serial scan in thread-0 registers, next row prefetched
        if (tid == 0) {
            unsigned long long kw[WMAX];
            #pragma unroll
            for (int w = 0; w < WMAX; ++w) {
                int full = V - w * 64;
                kw[w] = (full >= 64) ? ~0ull : (full > 0 ? ((1ull << full) - 1ull) : 0ull);
            }
            unsigned long long rowb[WMAX], nxtb[WMAX];
            #pragma unroll
            for (int w = 0; w < WMAX; ++w) rowb[w] = (w < W) ? s_sup[w] : 0ull;
            #pragma unroll
            for (int w = 0; w < WMAX; ++w) {
                if (w * 64 < V) {
                    unsigned long long cur = kw[w];
                    int lim = V - w * 64; if (lim > 64) lim = 64;
                    for (int b = 0; b < lim; ++b) {
                        int nxt = w * 64 + b + 1;           // prefetch next row
                        if (nxt < V) {
                            #pragma unroll
                            for (int w2 = 0; w2 < WMAX; ++w2)
                                if (w2 < W) nxtb[w2] = s_sup[nxt * W + w2];
                        }
                        if ((cur >> b) & 1ull) {
                            cur &= ~rowb[w];
                            #pragma unroll
                            for (int w2 = 0; w2 < WMAX; ++w2)
                                if (w2 > w && w2 < W) kw[w2] &= ~rowb[w2];
                        }
                        #pragma unroll
                        for (int w2 = 0; w2 < WMAX; ++w2) rowb[w2] = nxtb[w2];
                    }
                    kw[w] = cur;
                }
            }
            #pragma unroll
            for (int w = 0; w < WMAX; ++w) s_kw[w] = kw[w];
        }
        __syncthreads();
    } else if (V > SUPMAX) {
        // fallback: sequential-i / parallel-j greedy (correct for any V)
        for (int p = tid; p < V; p += NTB) s_keepi[p] = 1;
        __syncthreads();
        for (int i = 0; i < V; ++i) {
            if (s_keepi[i]) {
                float ay0 = s_y0[i], ax0 = s_x0[i];
                float ay1 = s_y1[i], ax1 = s_x1[i];
                float aa  = s_area[i];
                for (int jj = i + 1 + tid; jj < V; jj += NTB) {
                    float ty = fmaxf(ay0, s_y0[jj]);
                    float tx = fmaxf(ax0, s_x0[jj]);
                    float by = fminf(ay1, s_y1[jj]);
                    float bx = fminf(ax1, s_x1[jj]);
                    float hh = fmaxf(by - ty, 0.f);
                    float ww = fmaxf(bx - tx, 0.f);
                    float inter = hh * ww;
                    float iou = inter / (aa + s_area[jj] - inter + 1e-9f);
                    if (iou > 0.5f) s_keepi[jj] = 0;
                }
            }
            __syncthreads();
        }
    }

    // ---- 5. write outputs (covers full buffer; no memset needed) ----
    const bool matrix_path = (V <= SUPMAX);
    float* out0 = out + (size_t)(c - 1) * R * 5;
    float* out1 = out + (size_t)80 * R * 5 + (size_t)(c - 1) * R;
    for (int p = tid; p < R; p += NTB) {
        bool kept = false;
        if (p < V)
            kept = matrix_path ? (((s_kw[p >> 6] >> (p & 63)) & 1ull) != 0ull)
                               : (s_keepi[p] != 0);
        float y0 = 0.f, x0 = 0.f, y1 = 0.f, x1 = 0.f, s = 0.f, lab = -1.0f;
        if (kept) {
            y0 = s_y0[p]; x0 = s_x0[p]; y1 = s_y1[p]; x1 = s_x1[p];
            s  = s_ss[p];
            lab = (float)(c - 1);
        }
        out0[p*5+0] = y0; out0[p*5+1] = x0; out0[p*5+2] = y1;
        out0[p*5+3] = x1; out0[p*5+4] = s;
        out1[p] = lab;
    }
}

extern "C" void kernel_launch(void* const* d_in, const int* in_sizes, int n_in,
                              void* d_out, int out_size, void* d_ws, size_t ws_size,
                              hipStream_t stream) {
    const float* roi       = (const float*)d_in[0];
    const float* roi_loc   = (const float*)d_in[1];
    const float* roi_score = (const float*)d_in[2];
    float* out   = (float*)d_out;
    float* probT = (float*)d_ws;          // [NC * PT_LD] = 332 KB

    hipLaunchKernelGGL(softmax_probT_kernel, dim3((R + 3) / 4), dim3(NTA), 0, stream,
                       roi_score, probT);
    hipLaunchKernelGGL(frcnn_classB_kernel, dim3(NC - 1), dim3(NTB), 0, stream,
                       roi, roi_loc, probT, out);
}